// Round 1
// baseline (522.673 us; speedup 1.0000x reference)
//
#include <hip/hip_runtime.h>
#include <hip/hip_bf16.h>

#define S_LEN 2048
#define NB    32      // batch
#define EMB   1024
#define ATT   512
#define HID   1024

typedef float f32x4  __attribute__((ext_vector_type(4)));
typedef short s16x8  __attribute__((ext_vector_type(8)));

static __device__ __forceinline__ short f2bf(float f) {
    return __builtin_bit_cast(short, __float2bfloat16(f));
}

static __device__ __forceinline__ float tanh_fast(float x) {
    float e = __expf(2.0f * x);
    return 1.0f - 2.0f / (e + 1.0f);
}

// ---------------- K1: hid_comb[b][a] = hid[b,:]@W_hid[:,a] + b_hid[a] + b_emb[a]
__global__ void k_hidcomb(const float* __restrict__ hid,
                          const float* __restrict__ W_hid,
                          const float* __restrict__ b_hid,
                          const float* __restrict__ b_emb,
                          float* __restrict__ hid_comb) {
    int gid = blockIdx.x * 256 + threadIdx.x;   // 32*512 = 16384
    int b = gid >> 9, a = gid & 511;
    const float* hr = hid + b * HID;
    float acc = 0.f;
#pragma unroll 4
    for (int k = 0; k < HID; ++k) acc += hr[k] * W_hid[k * ATT + a];
    hid_comb[gid] = acc + b_hid[a] + b_emb[a];
}

// ---------------- K2: W_T[a][k] = bf16(W_emb[k][a])
__global__ void k_wt(const float* __restrict__ W, unsigned short* __restrict__ WT) {
    __shared__ float tile[32][33];
    int k0 = blockIdx.x * 32, a0 = blockIdx.y * 32;
    int tx = threadIdx.x, ty = threadIdx.y;     // 32 x 8
#pragma unroll
    for (int i = 0; i < 32; i += 8)
        tile[ty + i][tx] = W[(size_t)(k0 + ty + i) * ATT + a0 + tx];
    __syncthreads();
#pragma unroll
    for (int i = 0; i < 32; i += 8)
        WT[(size_t)(a0 + ty + i) * HID + k0 + tx] =
            (unsigned short)f2bf(tile[tx][ty + i]);
}

// ---------------- K3: fused GEMM (emb @ W_emb, bf16 MFMA) + tanh + dot(att_v) -> scores
// grid 2048 blocks (512 m-tiles x 4 n-tiles), 256 threads = 4 waves (2x2), wave tile 64x64
__global__ __launch_bounds__(256) void k_gemm_scores(
        const float* __restrict__ emb,
        const unsigned short* __restrict__ WT,
        const float* __restrict__ hid_comb,
        const float* __restrict__ att_v,
        float* __restrict__ scores) {
    // XCD-aware swizzle: nwg=2048, 8 XCDs -> each XCD gets 256 consecutive tile ids
    int bid = blockIdx.x;
    int tid2 = (bid & 7) * 256 + (bid >> 3);
    int mt = tid2 >> 2, nt = tid2 & 3;
    int m0 = mt * 128, n0 = nt * 128;

    int lane  = threadIdx.x & 63;
    int wave  = threadIdx.x >> 6;
    int wr = wave >> 1, wc = wave & 1;
    int row_l = lane & 15;          // row (A) / col (B/D) within fragment
    int kg    = lane >> 4;          // k-group: k = kg*8 + i

    f32x4 acc[4][4] = {};

    const float* aBase[4];
    const unsigned short* bBase[4];
#pragma unroll
    for (int mf = 0; mf < 4; ++mf)
        aBase[mf] = emb + (size_t)(m0 + wr * 64 + mf * 16 + row_l) * EMB + kg * 8;
#pragma unroll
    for (int nf = 0; nf < 4; ++nf)
        bBase[nf] = WT + (size_t)(n0 + wc * 64 + nf * 16 + row_l) * HID + kg * 8;

    for (int kk = 0; kk < EMB; kk += 32) {
        s16x8 af[4], bfr[4];
#pragma unroll
        for (int mf = 0; mf < 4; ++mf) {
            const float* p = aBase[mf] + kk;
            f32x4 x0 = *(const f32x4*)(p);
            f32x4 x1 = *(const f32x4*)(p + 4);
            s16x8 r;
            r[0] = f2bf(x0[0]); r[1] = f2bf(x0[1]);
            r[2] = f2bf(x0[2]); r[3] = f2bf(x0[3]);
            r[4] = f2bf(x1[0]); r[5] = f2bf(x1[1]);
            r[6] = f2bf(x1[2]); r[7] = f2bf(x1[3]);
            af[mf] = r;
        }
#pragma unroll
        for (int nf = 0; nf < 4; ++nf)
            bfr[nf] = *(const s16x8*)(bBase[nf] + kk);
#pragma unroll
        for (int mf = 0; mf < 4; ++mf)
#pragma unroll
            for (int nf = 0; nf < 4; ++nf)
                acc[mf][nf] = __builtin_amdgcn_mfma_f32_16x16x32_bf16(
                    af[mf], bfr[nf], acc[mf][nf], 0, 0, 0);
    }

    // Epilogue: score partial for this 128-col slice
    float vv[4];
#pragma unroll
    for (int nf = 0; nf < 4; ++nf)
        vv[nf] = att_v[n0 + wc * 64 + nf * 16 + row_l];

#pragma unroll
    for (int mf = 0; mf < 4; ++mf) {
#pragma unroll
        for (int j = 0; j < 4; ++j) {
            int m = m0 + wr * 64 + mf * 16 + kg * 4 + j;   // D row
            int b = m & 31;
            int s = m >> 5;
            const float* ad = hid_comb + b * ATT + n0 + wc * 64;
            float sum = 0.f;
#pragma unroll
            for (int nf = 0; nf < 4; ++nf) {
                float x = acc[mf][nf][j] + ad[nf * 16 + row_l];
                sum += tanh_fast(x) * vv[nf];
            }
#pragma unroll
            for (int d = 1; d < 16; d <<= 1)
                sum += __shfl_xor(sum, d, 64);
            if (row_l == 0)
                atomicAdd(&scores[b * S_LEN + s], sum);
        }
    }
}

// ---------------- K4: softmax over S per batch row; weights -> d_out
__global__ void k_softmax(const float* __restrict__ scores,
                          float* __restrict__ weights) {
    int b = blockIdx.x, tid = threadIdx.x;  // 256 threads
    float v[8];
    float mx = -1e30f;
#pragma unroll
    for (int i = 0; i < 8; ++i) {
        v[i] = scores[b * S_LEN + i * 256 + tid];
        mx = fmaxf(mx, v[i]);
    }
#pragma unroll
    for (int d = 1; d < 64; d <<= 1) mx = fmaxf(mx, __shfl_xor(mx, d, 64));
    __shared__ float sm[4], ss[4];
    if ((tid & 63) == 0) sm[tid >> 6] = mx;
    __syncthreads();
    mx = fmaxf(fmaxf(sm[0], sm[1]), fmaxf(sm[2], sm[3]));
    float sum = 0.f;
#pragma unroll
    for (int i = 0; i < 8; ++i) {
        v[i] = __expf(v[i] - mx);
        sum += v[i];
    }
#pragma unroll
    for (int d = 1; d < 64; d <<= 1) sum += __shfl_xor(sum, d, 64);
    if ((tid & 63) == 0) ss[tid >> 6] = sum;
    __syncthreads();
    sum = ss[0] + ss[1] + ss[2] + ss[3];
    float inv = 1.0f / sum;
#pragma unroll
    for (int i = 0; i < 8; ++i)
        weights[b * S_LEN + i * 256 + tid] = v[i] * inv;
}

// ---------------- K5: context partials over s-chunks
// grid (16 schunks, 32 b), 256 threads; thread t covers e = 4t..4t+3
__global__ void k_ctx1(const float* __restrict__ emb,
                       const float* __restrict__ weights,
                       float* __restrict__ part) {
    int sc = blockIdx.x, b = blockIdx.y, t = threadIdx.x;
    const f32x4* ep = (const f32x4*)emb;
    f32x4 acc = {0.f, 0.f, 0.f, 0.f};
    int s0 = sc * 128;
    for (int i = 0; i < 128; i += 4) {
#pragma unroll
        for (int u = 0; u < 4; ++u) {
            int s = s0 + i + u;
            float w = weights[b * S_LEN + s];
            f32x4 x = ep[(size_t)(s * NB + b) * 256 + t];
            acc += w * x;
        }
    }
    ((f32x4*)part)[(size_t)(sc * NB + b) * 256 + t] = acc;
}

// ---------------- K6: reduce partials -> context (d_out front)
__global__ void k_ctx2(const float* __restrict__ part, float* __restrict__ ctx) {
    int i = blockIdx.x * 256 + threadIdx.x;   // 32*1024
    float s = 0.f;
#pragma unroll
    for (int sc = 0; sc < 16; ++sc) s += part[sc * (NB * EMB) + i];
    ctx[i] = s;
}

extern "C" void kernel_launch(void* const* d_in, const int* in_sizes, int n_in,
                              void* d_out, int out_size, void* d_ws, size_t ws_size,
                              hipStream_t stream) {
    const float* hid   = (const float*)d_in[0];
    const float* emb   = (const float*)d_in[1];
    const float* W_hid = (const float*)d_in[2];
    const float* b_hid = (const float*)d_in[3];
    const float* W_emb = (const float*)d_in[4];
    const float* b_emb = (const float*)d_in[5];
    const float* att_v = (const float*)d_in[6];

    float* out     = (float*)d_out;
    float* ctx     = out;                // 32*1024
    float* weights = out + NB * EMB;     // 32*2048

    char* ws = (char*)d_ws;
    float*          scores   = (float*)(ws);                 // 256 KB
    float*          hid_comb = (float*)(ws + 262144);        // 64 KB
    unsigned short* WT       = (unsigned short*)(ws + 327680); // 1 MB
    float*          part     = (float*)(ws + 1376256);       // 2 MB

    hipMemsetAsync(scores, 0, NB * S_LEN * sizeof(float), stream);
    k_hidcomb<<<64, 256, 0, stream>>>(hid, W_hid, b_hid, b_emb, hid_comb);
    k_wt<<<dim3(32, 16), dim3(32, 8), 0, stream>>>(W_emb, WT);
    k_gemm_scores<<<2048, 256, 0, stream>>>(emb, WT, hid_comb, att_v, scores);
    k_softmax<<<NB, 256, 0, stream>>>(scores, weights);
    k_ctx1<<<dim3(16, NB), 256, 0, stream>>>(emb, weights, part);
    k_ctx2<<<128, 256, 0, stream>>>(part, ctx);
}

// Round 2
// 314.384 us; speedup vs baseline: 1.6625x; 1.6625x over previous
//
#include <hip/hip_runtime.h>
#include <hip/hip_bf16.h>

#define S_LEN 2048
#define NB    32      // batch
#define EMB   1024
#define ATT   512
#define HID   1024

typedef float f32x4  __attribute__((ext_vector_type(4)));
typedef short s16x4  __attribute__((ext_vector_type(4)));
typedef short s16x8  __attribute__((ext_vector_type(8)));

static __device__ __forceinline__ short f2bf(float f) {
    return __builtin_bit_cast(short, __float2bfloat16(f));
}

static __device__ __forceinline__ float tanh_fast(float x) {
    float e = __expf(2.0f * x);
    return 1.0f - 2.0f / (e + 1.0f);
}

#define GLOAD_LDS16(gp, lp)                                                   \
    __builtin_amdgcn_global_load_lds(                                         \
        (const __attribute__((address_space(1))) void*)(gp),                  \
        (__attribute__((address_space(3))) void*)(uintptr_t)(lp), 16, 0, 0)

// ---------------- K1: hid_comb[b][a] = hid[b,:]@W_hid[:,a] + b_hid[a] + b_emb[a]
__global__ void k_hidcomb(const float* __restrict__ hid,
                          const float* __restrict__ W_hid,
                          const float* __restrict__ b_hid,
                          const float* __restrict__ b_emb,
                          float* __restrict__ hid_comb) {
    int gid = blockIdx.x * 256 + threadIdx.x;   // 32*512 = 16384
    int b = gid >> 9, a = gid & 511;
    const float* hr = hid + b * HID;
    float acc = 0.f;
#pragma unroll 4
    for (int k = 0; k < HID; ++k) acc += hr[k] * W_hid[k * ATT + a];
    hid_comb[gid] = acc + b_hid[a] + b_emb[a];
}

// ---------------- K2: W_T[a][k] = bf16(W_emb[k][a])
__global__ void k_wt(const float* __restrict__ W, unsigned short* __restrict__ WT) {
    __shared__ float tile[32][33];
    int k0 = blockIdx.x * 32, a0 = blockIdx.y * 32;
    int tx = threadIdx.x, ty = threadIdx.y;     // 32 x 8
#pragma unroll
    for (int i = 0; i < 32; i += 8)
        tile[ty + i][tx] = W[(size_t)(k0 + ty + i) * ATT + a0 + tx];
    __syncthreads();
#pragma unroll
    for (int i = 0; i < 32; i += 8)
        WT[(size_t)(a0 + ty + i) * HID + k0 + tx] =
            (unsigned short)f2bf(tile[tx][ty + i]);
}

// ---------------- K3: fused GEMM (emb @ W_emb, bf16 MFMA) + tanh + dot(att_v)
// 128x128 tile, BK=32, 4 waves each owning a 32x128 slice (no cross-wave combine).
// A: reg-staged f32 -> cvt bf16 -> swizzled LDS.  B: global_load_lds w/ pre-swizzled src.
__global__ __launch_bounds__(256) void k_gemm_scores(
        const float* __restrict__ emb,
        const unsigned short* __restrict__ WT,
        const float* __restrict__ hid_comb,
        const float* __restrict__ att_v,
        float* __restrict__ part) {           // part[nt][b][s], nt=0..3
    __shared__ __align__(16) unsigned short lA[128 * 32];  // 8KB, swizzled
    __shared__ __align__(16) unsigned short lB[128 * 32];  // 8KB, swizzled

    // XCD swizzle: 2048 wgs, 8 XCDs; XCD x gets 256 consecutive tile ids ->
    // the 4 n-tiles of each m-panel share an XCD L2.
    int bid = blockIdx.x;
    int t2 = (bid & 7) * 256 + (bid >> 3);
    int mt = t2 >> 2, nt = t2 & 3;
    int m0 = mt * 128, n0 = nt * 128;

    int tid  = threadIdx.x;
    int lane = tid & 63, wave = tid >> 6;
    int row_l = lane & 15;        // fragment row (A) / col (B,D)
    int kg    = lane >> 4;        // k-group: k = kg*8 + i

    // ---- A staging: 4 chunks/thread; chunk ci = i*256+tid; row=ci>>3 slot=ci&7 (4 f32)
    int ar[4], ac[4], awoff[4];
#pragma unroll
    for (int i = 0; i < 4; ++i) {
        int ci = i * 256 + tid;
        ar[i] = ci >> 3;
        ac[i] = (ci & 7) * 4;
        int slot = ci & 7;
        int ch = (slot >> 1) ^ ((ar[i] >> 1) & 3);        // 16B-chunk swizzle
        awoff[i] = ar[i] * 64 + ch * 16 + (slot & 1) * 8; // byte offset
    }
    const float* abase = emb + (size_t)m0 * EMB;

    // ---- B staging (global_load_lds, linear dest, pre-swizzled source)
    const unsigned short* bbase = WT + (size_t)n0 * HID;
    int brow[2], bsrcch[2], bdst[2];
#pragma unroll
    for (int j = 0; j < 2; ++j) {
        int c = j * 256 + tid;                 // 16B chunk id
        int row = c >> 2, ch = c & 3;
        brow[j] = row;
        bsrcch[j] = ch ^ ((row >> 1) & 3);
        bdst[j] = c * 16;
    }

    // ---- fragment read offsets (swizzled)
    int aoff[2], boff[8];
#pragma unroll
    for (int mf = 0; mf < 2; ++mf) {
        int row = wave * 32 + mf * 16 + row_l;
        aoff[mf] = row * 64 + ((kg ^ ((row >> 1) & 3)) * 16);
    }
#pragma unroll
    for (int nf = 0; nf < 8; ++nf) {
        int row = nf * 16 + row_l;
        boff[nf] = row * 64 + ((kg ^ ((row >> 1) & 3)) * 16);
    }

    f32x4 acc[2][8] = {};
    f32x4 areg[4];
#pragma unroll
    for (int i = 0; i < 4; ++i)
        areg[i] = *(const f32x4*)(abase + (size_t)ar[i] * EMB + ac[i]);

    for (int kk = 0; kk < EMB; kk += 32) {
        __syncthreads();   // all waves done reading previous tile (also drains prefetch)
        // A: cvt + swizzled LDS write
#pragma unroll
        for (int i = 0; i < 4; ++i) {
            s16x4 w;
            w[0] = f2bf(areg[i][0]); w[1] = f2bf(areg[i][1]);
            w[2] = f2bf(areg[i][2]); w[3] = f2bf(areg[i][3]);
            *(s16x4*)((char*)lA + awoff[i]) = w;
        }
        // B: async global->LDS
#pragma unroll
        for (int j = 0; j < 2; ++j)
            GLOAD_LDS16(bbase + (size_t)brow[j] * HID + kk + bsrcch[j] * 8,
                        (char*)lB + bdst[j]);
        __syncthreads();   // drains vmcnt+lgkmcnt: tiles ready

        // prefetch next A chunk while MFMA phase runs
        int kn = (kk + 32 < EMB) ? kk + 32 : 0;
#pragma unroll
        for (int i = 0; i < 4; ++i)
            areg[i] = *(const f32x4*)(abase + (size_t)ar[i] * EMB + kn + ac[i]);

        s16x8 af[2], bf[8];
#pragma unroll
        for (int mf = 0; mf < 2; ++mf)
            af[mf] = *(const s16x8*)((const char*)lA + aoff[mf]);
#pragma unroll
        for (int nf = 0; nf < 8; ++nf)
            bf[nf] = *(const s16x8*)((const char*)lB + boff[nf]);
#pragma unroll
        for (int mf = 0; mf < 2; ++mf)
#pragma unroll
            for (int nf = 0; nf < 8; ++nf)
                acc[mf][nf] = __builtin_amdgcn_mfma_f32_16x16x32_bf16(
                    af[mf], bf[nf], acc[mf][nf], 0, 0, 0);
    }

    // ---- epilogue: score partial for this 128-col slice
    float vv[8];
#pragma unroll
    for (int nf = 0; nf < 8; ++nf)
        vv[nf] = att_v[n0 + nf * 16 + row_l];

#pragma unroll
    for (int mf = 0; mf < 2; ++mf) {
#pragma unroll
        for (int j = 0; j < 4; ++j) {
            int m = m0 + wave * 32 + mf * 16 + kg * 4 + j;   // D row
            int b = m & 31;
            int s = m >> 5;
            const float* ad = hid_comb + b * ATT + n0;
            float sum = 0.f;
#pragma unroll
            for (int nf = 0; nf < 8; ++nf) {
                float x = acc[mf][nf][j] + ad[nf * 16 + row_l];
                sum += tanh_fast(x) * vv[nf];
            }
#pragma unroll
            for (int d = 1; d < 16; d <<= 1)
                sum += __shfl_xor(sum, d, 64);
            if (row_l == 0)
                part[nt * (NB * S_LEN) + b * S_LEN + s] = sum;
        }
    }
}

// ---------------- K4: softmax over S per batch row (sums the 4 n-slices)
__global__ void k_softmax(const float* __restrict__ part,
                          float* __restrict__ weights) {
    int b = blockIdx.x, tid = threadIdx.x;  // 256 threads
    float v[8];
    float mx = -1e30f;
#pragma unroll
    for (int i = 0; i < 8; ++i) {
        int s = i * 256 + tid;
        float sc = part[0 * (NB * S_LEN) + b * S_LEN + s]
                 + part[1 * (NB * S_LEN) + b * S_LEN + s]
                 + part[2 * (NB * S_LEN) + b * S_LEN + s]
                 + part[3 * (NB * S_LEN) + b * S_LEN + s];
        v[i] = sc;
        mx = fmaxf(mx, sc);
    }
#pragma unroll
    for (int d = 1; d < 64; d <<= 1) mx = fmaxf(mx, __shfl_xor(mx, d, 64));
    __shared__ float sm[4], ss[4];
    if ((tid & 63) == 0) sm[tid >> 6] = mx;
    __syncthreads();
    mx = fmaxf(fmaxf(sm[0], sm[1]), fmaxf(sm[2], sm[3]));
    float sum = 0.f;
#pragma unroll
    for (int i = 0; i < 8; ++i) {
        v[i] = __expf(v[i] - mx);
        sum += v[i];
    }
#pragma unroll
    for (int d = 1; d < 64; d <<= 1) sum += __shfl_xor(sum, d, 64);
    if ((tid & 63) == 0) ss[tid >> 6] = sum;
    __syncthreads();
    sum = ss[0] + ss[1] + ss[2] + ss[3];
    float inv = 1.0f / sum;
#pragma unroll
    for (int i = 0; i < 8; ++i)
        weights[b * S_LEN + i * 256 + tid] = v[i] * inv;
}

// ---------------- K5: context partials over s-chunks
__global__ void k_ctx1(const float* __restrict__ emb,
                       const float* __restrict__ weights,
                       float* __restrict__ cpart) {
    int sc = blockIdx.x, b = blockIdx.y, t = threadIdx.x;
    const f32x4* ep = (const f32x4*)emb;
    f32x4 acc = {0.f, 0.f, 0.f, 0.f};
    int s0 = sc * 128;
    for (int i = 0; i < 128; i += 4) {
#pragma unroll
        for (int u = 0; u < 4; ++u) {
            int s = s0 + i + u;
            float w = weights[b * S_LEN + s];
            f32x4 x = ep[(size_t)(s * NB + b) * 256 + t];
            acc += w * x;
        }
    }
    ((f32x4*)cpart)[(size_t)(sc * NB + b) * 256 + t] = acc;
}

// ---------------- K6: reduce partials -> context (d_out front)
__global__ void k_ctx2(const float* __restrict__ cpart, float* __restrict__ ctx) {
    int i = blockIdx.x * 256 + threadIdx.x;   // 32*1024
    float s = 0.f;
#pragma unroll
    for (int sc = 0; sc < 16; ++sc) s += cpart[sc * (NB * EMB) + i];
    ctx[i] = s;
}

extern "C" void kernel_launch(void* const* d_in, const int* in_sizes, int n_in,
                              void* d_out, int out_size, void* d_ws, size_t ws_size,
                              hipStream_t stream) {
    const float* hid   = (const float*)d_in[0];
    const float* emb   = (const float*)d_in[1];
    const float* W_hid = (const float*)d_in[2];
    const float* b_hid = (const float*)d_in[3];
    const float* W_emb = (const float*)d_in[4];
    const float* b_emb = (const float*)d_in[5];
    const float* att_v = (const float*)d_in[6];

    float* out     = (float*)d_out;
    float* ctx     = out;                // 32*1024
    float* weights = out + NB * EMB;     // 32*2048

    char* ws = (char*)d_ws;
    float*          part     = (float*)(ws);                    // 1 MB (4 score slices)
    float*          hid_comb = (float*)(ws + 1048576);          // 64 KB
    unsigned short* WT       = (unsigned short*)(ws + 1114112); // 1 MB (gemm phase)
    float*          cpart    = (float*)(ws + 1114112);          // 2 MB (ctx phase, reuses WT)

    k_hidcomb<<<64, 256, 0, stream>>>(hid, W_hid, b_hid, b_emb, hid_comb);
    k_wt<<<dim3(32, 16), dim3(32, 8), 0, stream>>>(W_emb, WT);
    k_gemm_scores<<<2048, 256, 0, stream>>>(emb, WT, hid_comb, att_v, part);
    k_softmax<<<NB, 256, 0, stream>>>(part, weights);
    k_ctx1<<<dim3(16, NB), 256, 0, stream>>>(emb, weights, cpart);
    k_ctx2<<<128, 256, 0, stream>>>(cpart, ctx);
}